// Round 6
// baseline (217.951 us; speedup 1.0000x reference)
//
#include <hip/hip_runtime.h>
#include <math.h>

// ---------------- problem constants ----------------
#define NROWS  23328           // 8 * 54 * 54
#define SPAT   2916            // 54*54 rows per batch
#define HIN    56
#define IMG    3136            // 56*56
#define CIMG   200704          // 64*3136
#define NOUT   2985984         // 23328*128
#define RBPB   46              // 64-row blocks per batch (last has 36 valid)
#define NKP    3               // K-pieces (thirds)
#define NCH    18              // chunks per K-piece (216 planes / 12)

// ---------------- ws layout (bytes) ----------------
#define W2_OFF    0u                         // [648][128][8] bf16 = 1327104
#define SILU_OFF  1327104u                   // [NHW][64] bf16 = 3211264
#define WS_NEED   (SILU_OFF + 3211264u)      // 4.5 MB (tiny; ws >= 268 MB observed)

// prep idx ranges
#define R_SIL_END  200704
#define R_W2_END   864256                    // +663552
#define R_ZERO_END 1610752                   // +746496 (NOUT/4 float4 zeroes)

typedef __bf16 bf16x8 __attribute__((ext_vector_type(8)));
typedef float  floatx4 __attribute__((ext_vector_type(4)));

#define GL2LDS(SRC, DST) __builtin_amdgcn_global_load_lds( \
    (const __attribute__((address_space(1))) unsigned int*)(SRC), \
    (__attribute__((address_space(3))) unsigned int*)(DST), 16, 0, 0)

__device__ __forceinline__ float silu_f(float p) {
    return p / (1.f + __expf(-p));
}

__device__ __forceinline__ bf16x8 bases8(float p) {
    float u  = p * 2.5f + 5.5f;              // uniform grid [-2.2,2.2], h=0.4
    float fk = floorf(u);
    int   kk = (int)fk;
    float t  = u - fk;
    float t2 = t * t, t3 = t2 * t;
    float omt = 1.f - t;
    float w0 = omt * omt * omt * (1.f / 6.f);
    float w1 = (3.f * t3 - 6.f * t2 + 4.f) * (1.f / 6.f);
    float w2 = (-3.f * t3 + 3.f * t2 + 3.f * t + 1.f) * (1.f / 6.f);
    float w3 = t3 * (1.f / 6.f);
    bool inr = (u >= 0.f) && (u < 11.f);
    bf16x8 v;
#pragma unroll
    for (int g = 0; g < 8; ++g) {
        int d = kk - g;
        float val = (d == 3) ? w0 : (d == 2) ? w1
                  : (d == 1) ? w2 : (d == 0) ? w3 : 0.f;
        v[g] = (__bf16)(inr ? val : 0.f);
    }
    return v;
}

// ---------------------------------------------------------------------------
// Prep (round-6): silu transpose + W2 planes + ZERO the output (for the
// atomic-accumulate gemm). act8 materialization removed — the gemm computes
// spline bases on the fly from x (saves 25.7 MB write + ~238 MB L2 re-read
// and shrinks the gemm's per-XCD working set below the 4 MiB L2).
// ---------------------------------------------------------------------------
__global__ __launch_bounds__(256) void prep_kernel(
    const float* __restrict__ x, const float* __restrict__ bw,
    const float* __restrict__ sw, const float* __restrict__ sc,
    char* __restrict__ ws, float* __restrict__ outp)
{
    __bf16* W2    = (__bf16*)(ws + W2_OFF);
    __bf16* silu_t= (__bf16*)(ws + SILU_OFF);

    int idx = blockIdx.x * 256 + threadIdx.x;
    if (idx < R_SIL_END) {
        int c8 = idx & 7;
        int r  = idx >> 3;                   // b*IMG + hw
        int b  = r / IMG;
        int hw = r - b * IMG;
        const float* xb = x + b * CIMG + (c8 * 8) * IMG + hw;
        bf16x8 v;
#pragma unroll
        for (int j = 0; j < 8; ++j) v[j] = (__bf16)silu_f(xb[j * IMG]);
        *(bf16x8*)(silu_t + (size_t)r * 64 + c8 * 8) = v;
    } else if (idx < R_W2_END) {
        int iw = idx - R_SIL_END;
        int j  = iw & 7;
        int o  = (iw >> 3) & 127;
        int g  = iw >> 10;                   // 0..647
        float val;
        if (g < 576) {
            val = sw[(o * 576 + g) * 8 + j] * sc[o * 576 + g];
        } else {
            int eb = g - 576;
            int rs = eb >> 3;
            int c  = (eb & 7) * 8 + j;
            val = bw[o * 576 + c * 9 + rs];
        }
        W2[iw] = (__bf16)val;
    } else if (idx < R_ZERO_END) {
        int i4 = idx - R_W2_END;             // NOUT/4 float4 stores
        ((floatx4*)outp)[i4] = (floatx4){0.f, 0.f, 0.f, 0.f};
    }
}

// ---------------------------------------------------------------------------
// GEMM: 1104 blocks = 8 batches x 46 row-blocks x 3 K-pieces, 256 threads
// (4 waves). batch = blockIdx & 7 -> batch-per-XCD L2 residency.
// Block = 64 rows x 128 couts x K-third; wave = 64 rows x 32 couts (acc 4x2).
//
// Round-6 changes (auxiliary-work elimination; gemm schedule frozen at r5):
//  * Spline A-planes (g<576, chunks 0..47) are computed IN staging: load
//    x[pb+off] (4 B/lane, coalesced), bases8 (~40 VALU), ds_write_b128.
//    Branch is wave-uniform; spline/silu chunks never mix (576 = 48*12).
//    Silu planes (g>=576, chunks 48..53) still gl2lds from silu_t.
//  * Output accumulated with atomicAdd (out zeroed in prep): no partials,
//    no reduce kernel. 3 atomics per output, coalesced 64 B runs.
// ---------------------------------------------------------------------------
__global__ __launch_bounds__(256, 4) void kan_gemm(
    const float* __restrict__ x, char* __restrict__ ws,
    float* __restrict__ outp)
{
    const __bf16* W2     = (const __bf16*)(ws + W2_OFF);
    const __bf16* silu_t = (const __bf16*)(ws + SILU_OFF);

    __shared__ __align__(16) char As[2][12 * 64 * 16];   // 2 x 12,288 B

    const int tid   = threadIdx.x;
    const int lane  = tid & 63;
    const int wave  = tid >> 6;          // 0..3 = coutg
    const int quad  = lane >> 4;
    const int l16   = lane & 15;

    const int batch = blockIdx.x & 7;    // XCD affinity (round-robin %8)
    const int t2    = blockIdx.x >> 3;   // 0..137
    const int kp    = t2 % 3;            // K-piece
    const int rb    = t2 / 3;            // 0..45
    const int row0  = rb * 64;           // within batch

    // staging identity: lane = local row, clamped to batch range
    const int rl0 = row0 + lane;
    const int rcl = rl0 < SPAT ? rl0 : SPAT - 1;
    const int ohh = rcl / 54, oww = rcl - (rcl / 54) * 54;
    const size_t pb = (size_t)batch * CIMG + ohh * HIN + oww;  // pixel index
    const size_t sb = ((size_t)batch * IMG + ohh * HIN + oww) * 64;

    floatx4 acc[4][2] = {};

    // chunk = 12 planes x 64 rows x 16 B. Wave w handles planes {t*4+w}.
    // Spline planes: fused bases8 (x -> VALU -> ds_write). Silu: gl2lds.
    auto stage = [&](int chunkAbs, int buf) {
        int gbase = chunkAbs * 12;
#pragma unroll
        for (int t = 0; t < 3; ++t) {
            int p = t * 4 + wave;            // plane 0..11 (wave-uniform)
            int g = gbase + p;               // global k/8 index 0..647
            if (g < 576) {                   // spline planes: fused compute
                int c  = g / 9;
                int rs = g - 9 * c;
                int rw = rs / 3;
                int off = c * IMG + rw * HIN + (rs - rw * 3);
                float xv = x[pb + off];
                *(bf16x8*)&As[buf][p * 1024 + lane * 16] = bases8(xv);
            } else {                         // base/silu planes: async copy
                int eb = g - 576;
                int rs = eb >> 3;
                int rw = rs / 3;
                int off = (rw * HIN + (rs - rw * 3)) * 64 + (eb & 7) * 8;
                GL2LDS((const char*)(silu_t + sb + off), &As[buf][p * 1024]);
            }
        }
    };

    auto mfma_chunk = [&](int chunkAbs, int buf) {
        const char* Ab = (const char*)As[buf];
#pragma unroll
        for (int ks = 0; ks < 3; ++ks) {
            int gq = (chunkAbs * 3 + ks) * 4 + quad;
            bf16x8 wfr[2], afr[4];
#pragma unroll
            for (int nt = 0; nt < 2; ++nt)
                wfr[nt] = *(const bf16x8*)(W2 +
                    ((size_t)gq * 128 + wave * 32 + nt * 16 + l16) * 8);
#pragma unroll
            for (int mt = 0; mt < 4; ++mt)
                afr[mt] = *(const bf16x8*)(Ab +
                    ((ks * 4 + quad) * 64 + mt * 16 + l16) * 16);
#pragma unroll
            for (int mt = 0; mt < 4; ++mt)
#pragma unroll
                for (int nt = 0; nt < 2; ++nt)
                    acc[mt][nt] = __builtin_amdgcn_mfma_f32_16x16x32_bf16(
                        wfr[nt], afr[mt], acc[mt][nt], 0, 0, 0);
        }
    };

    const int cstart = kp * NCH;

    stage(cstart, 0);
    __syncthreads();

    for (int i = 0; i < NCH; ++i) {
        const int buf = i & 1;
        if (i + 1 < NCH) stage(cstart + i + 1, buf ^ 1);   // prefetch
        mfma_chunk(cstart + i, buf);
        __syncthreads();
    }

    // epilogue: atomic accumulate (out pre-zeroed in prep).
    // D col(l16) = local row, D row(quad*4+r) = cout -> coalesced 64 B runs.
#pragma unroll
    for (int mt = 0; mt < 4; ++mt) {
        int rl = row0 + mt * 16 + l16;       // row within batch
        if (rl < SPAT) {
#pragma unroll
            for (int nt = 0; nt < 2; ++nt) {
#pragma unroll
                for (int r = 0; r < 4; ++r) {
                    int o = wave * 32 + nt * 16 + quad * 4 + r;
                    size_t idx = (size_t)(batch * 128 + o) * SPAT + rl;
                    atomicAdd(&outp[idx], acc[mt][nt][r]);
                }
            }
        }
    }
}

extern "C" void kernel_launch(void* const* d_in, const int* in_sizes, int n_in,
                              void* d_out, int out_size, void* d_ws, size_t ws_size,
                              hipStream_t stream) {
    const float* x  = (const float*)d_in[0];
    const float* bw = (const float*)d_in[1];
    const float* sw = (const float*)d_in[2];
    const float* sc = (const float*)d_in[3];
    float* out = (float*)d_out;
    char*  ws  = (char*)d_ws;

    prep_kernel<<<R_ZERO_END / 256, 256, 0, stream>>>(x, bw, sw, sc, ws, out);
    kan_gemm<<<8 * RBPB * NKP, 256, 0, stream>>>(x, ws, out);
}

// Round 7
// 140.639 us; speedup vs baseline: 1.5497x; 1.5497x over previous
//
#include <hip/hip_runtime.h>
#include <math.h>

// ---------------- problem constants ----------------
#define NROWS  23328           // 8 * 54 * 54
#define SPAT   2916            // 54*54 rows per batch
#define HIN    56
#define IMG    3136            // 56*56
#define CIMG   200704          // 64*3136
#define NOUT   2985984         // 23328*128
#define RBPB   46              // 64-row blocks per batch (last has 36 valid)
#define NKP    6               // K-pieces (sixths)
#define NCH    9               // chunks per K-piece (54 chunks / 6)

// ---------------- ws layout (bytes) ----------------
#define W2_OFF    0u                         // [648][128][8] bf16 = 1327104
#define ACT8_OFF  1335296u                   // [NPIX][8] bf16 = 25690112
#define SILU_OFF  27025408u                  // [NHW][64] bf16 = 3211264
#define PART_OFF  30236672u                  // [6][NOUT] f32 = 71663616
#define WS_NEED   (PART_OFF + 6u * NOUT * 4u)   // 101.9 MB (268 MB observed)

// prep idx ranges
#define R_SIL_END  200704
#define R_W2_END   864256                    // +663552
#define R_ACT_END  1265664                   // +401408

typedef __bf16 bf16x8 __attribute__((ext_vector_type(8)));
typedef float  floatx4 __attribute__((ext_vector_type(4)));

#define GL2LDS(SRC, DST) __builtin_amdgcn_global_load_lds( \
    (const __attribute__((address_space(1))) unsigned int*)(SRC), \
    (__attribute__((address_space(3))) unsigned int*)(DST), 16, 0, 0)

__device__ __forceinline__ float silu_f(float p) {
    return p / (1.f + __expf(-p));
}

__device__ __forceinline__ bf16x8 bases8(float p) {
    float u  = p * 2.5f + 5.5f;              // uniform grid [-2.2,2.2], h=0.4
    float fk = floorf(u);
    int   kk = (int)fk;
    float t  = u - fk;
    float t2 = t * t, t3 = t2 * t;
    float omt = 1.f - t;
    float w0 = omt * omt * omt * (1.f / 6.f);
    float w1 = (3.f * t3 - 6.f * t2 + 4.f) * (1.f / 6.f);
    float w2 = (-3.f * t3 + 3.f * t2 + 3.f * t + 1.f) * (1.f / 6.f);
    float w3 = t3 * (1.f / 6.f);
    bool inr = (u >= 0.f) && (u < 11.f);
    bf16x8 v;
#pragma unroll
    for (int g = 0; g < 8; ++g) {
        int d = kk - g;
        float val = (d == 3) ? w0 : (d == 2) ? w1
                  : (d == 1) ? w2 : (d == 0) ? w3 : 0.f;
        v[g] = (__bf16)(inr ? val : 0.f);
    }
    return v;
}

// ---------------------------------------------------------------------------
// Prep: silu transpose, W2 planes ([g][cout][8], g = k/8), act8 planes.
// Round-5 version (act8 materialized — round 6 proved fusing it into the
// gemm destroys the async-stage property).
// ---------------------------------------------------------------------------
__global__ __launch_bounds__(256) void prep_kernel(
    const float* __restrict__ x, const float* __restrict__ bw,
    const float* __restrict__ sw, const float* __restrict__ sc,
    char* __restrict__ ws)
{
    __bf16* W2    = (__bf16*)(ws + W2_OFF);
    __bf16* act8  = (__bf16*)(ws + ACT8_OFF);
    __bf16* silu_t= (__bf16*)(ws + SILU_OFF);

    int idx = blockIdx.x * 256 + threadIdx.x;
    if (idx < R_SIL_END) {
        int c8 = idx & 7;
        int r  = idx >> 3;                   // b*IMG + hw
        int b  = r / IMG;
        int hw = r - b * IMG;
        const float* xb = x + b * CIMG + (c8 * 8) * IMG + hw;
        bf16x8 v;
#pragma unroll
        for (int j = 0; j < 8; ++j) v[j] = (__bf16)silu_f(xb[j * IMG]);
        *(bf16x8*)(silu_t + (size_t)r * 64 + c8 * 8) = v;
    } else if (idx < R_W2_END) {
        int iw = idx - R_SIL_END;
        int j  = iw & 7;
        int o  = (iw >> 3) & 127;
        int g  = iw >> 10;                   // 0..647
        float val;
        if (g < 576) {
            val = sw[(o * 576 + g) * 8 + j] * sc[o * 576 + g];
        } else {
            int eb = g - 576;
            int rs = eb >> 3;
            int c  = (eb & 7) * 8 + j;
            val = bw[o * 576 + c * 9 + rs];
        }
        W2[iw] = (__bf16)val;
    } else if (idx < R_ACT_END) {
        int i4 = idx - R_W2_END;
        float4 p = ((const float4*)x)[i4];
        __bf16* dst = act8 + (size_t)i4 * 32;
        *(bf16x8*)(dst)      = bases8(p.x);
        *(bf16x8*)(dst + 8)  = bases8(p.y);
        *(bf16x8*)(dst + 16) = bases8(p.z);
        *(bf16x8*)(dst + 24) = bases8(p.w);
    }
}

// ---------------------------------------------------------------------------
// GEMM: 2208 blocks = 8 batches x 46 row-blocks x 6 K-pieces, 256 threads
// (4 waves). batch = blockIdx & 7 -> batch-per-XCD L2 residency.
// Block = 64 rows x 128 couts x K-sixth; wave = 64 rows x 32 couts (acc 4x2).
//
// Round-7 levers (round-5 structure otherwise frozen):
//  * NKP=6: 2208 blocks -> 6 blocks/CU resident (LDS-capped, 147 KB), i.e.
//    6 independent wave-streams per SIMD (a 4-wave block puts 1 wave on
//    each SIMD). Rounds 0-5 showed the barrier-to-barrier wall (~5-7k cyc)
//    is invariant under traffic/latency fixes while every pipe is <40%
//    busy; MFMA-pipe busy = waves_per_SIMD * 466cyc / wall, so the lever
//    that must move time is independent wave-streams. r5 had 4.3.
//  * All 6 W-fragment loads hoisted to chunk start as named regs: at
//    VGPR=40 the compiler serialized them ks-by-ks (3 x ~200cyc exposed
//    L2 latency per chunk); ~24 more VGPRs buy one overlapped latency.
// ---------------------------------------------------------------------------
template <int MODE>
__global__ __launch_bounds__(256, 4) void kan_gemm(
    char* __restrict__ ws, float* __restrict__ outp)
{
    const __bf16* W2     = (const __bf16*)(ws + W2_OFF);
    const __bf16* act8   = (const __bf16*)(ws + ACT8_OFF);
    const __bf16* silu_t = (const __bf16*)(ws + SILU_OFF);
    float*        part   = (float*)(ws + PART_OFF);

    __shared__ __align__(16) char As[2][12 * 64 * 16];   // 2 x 12,288 B

    const int tid   = threadIdx.x;
    const int lane  = tid & 63;
    const int wave  = tid >> 6;          // 0..3 = coutg
    const int quad  = lane >> 4;
    const int l16   = lane & 15;

    const int batch = blockIdx.x & 7;    // XCD affinity (round-robin %8)
    const int t2    = blockIdx.x >> 3;   // 0..275
    const int kp    = t2 % NKP;          // K-piece
    const int rb    = t2 / NKP;          // 0..45
    const int row0  = rb * 64;           // within batch

    // staging identity: lane = local row, clamped to batch range
    const int rl0 = row0 + lane;
    const int rcl = rl0 < SPAT ? rl0 : SPAT - 1;
    const int ohh = rcl / 54, oww = rcl - (rcl / 54) * 54;
    const size_t pb = (size_t)batch * CIMG + ohh * HIN + oww;  // pixel index
    const size_t sb = ((size_t)batch * IMG + ohh * HIN + oww) * 64;

    floatx4 acc[4][2] = {};

    // chunk = 12 planes x 64 rows x 16 B = 12 slots of 1 KB.
    // Wave w stages planes {t*4 + w : t=0..2} (wave-uniform LDS dest).
    auto stage = [&](int chunkAbs, int buf) {
        int gbase = chunkAbs * 12;
#pragma unroll
        for (int t = 0; t < 3; ++t) {
            int p = t * 4 + wave;            // plane 0..11
            int g = gbase + p;               // global k/8 index 0..647
            const char* src;
            if (g < 576) {                   // spline planes
                int c  = g / 9;
                int rs = g - 9 * c;
                int rw = rs / 3;
                int off = c * IMG + rw * HIN + (rs - rw * 3);
                src = (const char*)(act8 + (pb + off) * 8);
            } else {                         // base/silu planes
                int eb = g - 576;
                int rs = eb >> 3;
                int rw = rs / 3;
                int off = (rw * HIN + (rs - rw * 3)) * 64 + (eb & 7) * 8;
                src = (const char*)(silu_t + sb + off);
            }
            GL2LDS(src, &As[buf][p * 1024]);
        }
    };

    auto mfma_chunk = [&](int chunkAbs, int buf) {
        const char* Ab = (const char*)As[buf];
        // W fragment base for this thread: plane gq = chunkAbs*12 + ks*4
        // + quad, cout = wave*32 + nt*16 + l16. Element offsets from base:
        // ks -> 4*128*8 = 4096, nt -> 16*8 = 128.
        const __bf16* Wb = W2 +
            ((size_t)(chunkAbs * 12 + quad) * 128 + wave * 32 + l16) * 8;
        // hoisted: all 6 W loads issue together (independent, ~1 latency)
        bf16x8 w00 = *(const bf16x8*)(Wb + 0 * 4096 + 0 * 128);
        bf16x8 w01 = *(const bf16x8*)(Wb + 0 * 4096 + 1 * 128);
        bf16x8 w10 = *(const bf16x8*)(Wb + 1 * 4096 + 0 * 128);
        bf16x8 w11 = *(const bf16x8*)(Wb + 1 * 4096 + 1 * 128);
        bf16x8 w20 = *(const bf16x8*)(Wb + 2 * 4096 + 0 * 128);
        bf16x8 w21 = *(const bf16x8*)(Wb + 2 * 4096 + 1 * 128);
#pragma unroll
        for (int ks = 0; ks < 3; ++ks) {
            bf16x8 wfr0 = (ks == 0) ? w00 : (ks == 1) ? w10 : w20;
            bf16x8 wfr1 = (ks == 0) ? w01 : (ks == 1) ? w11 : w21;
            bf16x8 afr[4];
#pragma unroll
            for (int mt = 0; mt < 4; ++mt)
                afr[mt] = *(const bf16x8*)(Ab +
                    ((ks * 4 + quad) * 64 + mt * 16 + l16) * 16);
#pragma unroll
            for (int mt = 0; mt < 4; ++mt) {
                acc[mt][0] = __builtin_amdgcn_mfma_f32_16x16x32_bf16(
                    wfr0, afr[mt], acc[mt][0], 0, 0, 0);
                acc[mt][1] = __builtin_amdgcn_mfma_f32_16x16x32_bf16(
                    wfr1, afr[mt], acc[mt][1], 0, 0, 0);
            }
        }
    };

    const int cstart = kp * NCH;

    stage(cstart, 0);
    __syncthreads();

    for (int i = 0; i < NCH; ++i) {
        const int buf = i & 1;
        if (i + 1 < NCH) stage(cstart + i + 1, buf ^ 1);   // async prefetch
        mfma_chunk(cstart + i, buf);
        __syncthreads();
    }

    // epilogue: D col(l16) = local row, D row(quad*4+r) = cout -> coalesced
#pragma unroll
    for (int mt = 0; mt < 4; ++mt) {
        int rl = row0 + mt * 16 + l16;       // row within batch
        if (rl < SPAT) {
#pragma unroll
            for (int nt = 0; nt < 2; ++nt) {
#pragma unroll
                for (int r = 0; r < 4; ++r) {
                    int o = wave * 32 + nt * 16 + quad * 4 + r;
                    size_t idx = (size_t)(batch * 128 + o) * SPAT + rl;
                    float v = acc[mt][nt][r];
                    if (MODE == 0) part[(size_t)kp * NOUT + idx] = v;
                    else           atomicAdd(&outp[idx], v);
                }
            }
        }
    }
}

__global__ __launch_bounds__(256) void reduce_kernel(
    const char* __restrict__ ws, float* __restrict__ outp)
{
    const floatx4* p = (const floatx4*)(ws + PART_OFF);
    int i = blockIdx.x * 256 + threadIdx.x;   // grid covers NOUT/4 exactly
    floatx4 s = p[i];
#pragma unroll
    for (int k = 1; k < NKP; ++k) {
        floatx4 v = p[(size_t)k * (NOUT / 4) + i];
        s[0] += v[0]; s[1] += v[1]; s[2] += v[2]; s[3] += v[3];
    }
    ((floatx4*)outp)[i] = s;
}

__global__ __launch_bounds__(256) void zero_kernel(float* __restrict__ outp)
{
    int i = blockIdx.x * 256 + threadIdx.x;
    ((floatx4*)outp)[i] = (floatx4){0.f, 0.f, 0.f, 0.f};
}

extern "C" void kernel_launch(void* const* d_in, const int* in_sizes, int n_in,
                              void* d_out, int out_size, void* d_ws, size_t ws_size,
                              hipStream_t stream) {
    const float* x  = (const float*)d_in[0];
    const float* bw = (const float*)d_in[1];
    const float* sw = (const float*)d_in[2];
    const float* sc = (const float*)d_in[3];
    float* out = (float*)d_out;
    char*  ws  = (char*)d_ws;

    prep_kernel<<<R_ACT_END / 256, 256, 0, stream>>>(x, bw, sw, sc, ws);

    if (ws_size >= WS_NEED) {
        kan_gemm<0><<<8 * RBPB * NKP, 256, 0, stream>>>(ws, out);
        reduce_kernel<<<NOUT / 4 / 256, 256, 0, stream>>>(ws, out);
    } else {
        zero_kernel<<<NOUT / 4 / 256, 256, 0, stream>>>(out);
        kan_gemm<1><<<8 * RBPB * NKP, 256, 0, stream>>>(ws, out);
    }
}